// Round 1
// baseline (324.881 us; speedup 1.0000x reference)
//
#include <hip/hip_runtime.h>

#define NB 8
#define NT 1024
#define ND 1024
#define NH 16
#define NDH 64
#define NM (NB*NT)   // 8192 rows
#define LNEPS 1e-5f

typedef __attribute__((ext_vector_type(8))) __bf16 bf16x8;
typedef __attribute__((ext_vector_type(4))) float f32x4;

// ---------------- W (K x N f32) -> WT (N x K bf16) ----------------
__global__ void transpose_to_bf16(const float* __restrict__ W, __bf16* __restrict__ WT) {
    __shared__ float tile[32][33];
    int bx = blockIdx.x * 32;  // n base
    int by = blockIdx.y * 32;  // k base
    int tx = threadIdx.x;      // 0..31
    int ty = threadIdx.y;      // 0..7
    for (int i = ty; i < 32; i += 8)
        tile[i][tx] = W[(size_t)(by + i) * ND + bx + tx];
    __syncthreads();
    for (int i = ty; i < 32; i += 8)
        WT[(size_t)(bx + i) * ND + by + tx] = (__bf16)tile[tx][i];
}

// ---------------- xsum[b,c] = sum_t x[b,t,c] ----------------
__global__ void xsum_kernel(const float* __restrict__ x, float* __restrict__ xsum) {
    int b = blockIdx.y;
    int c = blockIdx.x * 256 + threadIdx.x;
    const float* xp = x + (size_t)b * NT * ND + c;
    float s = 0.f;
    for (int t = 0; t < NT; ++t) s += xp[(size_t)t * ND];
    xsum[b * ND + c] = s;
}

// ------- per (b,h): ksum,vsum = xsum@Wk/Wv ; wqk = (Wq@ksum)/8 -------
__global__ void head_prep(const float* __restrict__ xsum,
                          const float* __restrict__ Wq, const float* __restrict__ Wk,
                          const float* __restrict__ Wv,
                          float* __restrict__ vsum, float* __restrict__ wqk) {
    int h = blockIdx.x, b = blockIdx.y;
    int t = threadIdx.x;
    int d = t & 63, q = t >> 6;  // quarter 0..3
    __shared__ float part[2][4][NDH];
    __shared__ float ks[NDH];
    const float* xs = xsum + b * ND;
    float sk = 0.f, sv = 0.f;
    for (int c = q * 256; c < q * 256 + 256; ++c) {
        float xv = xs[c];
        sk += xv * Wk[((size_t)h * ND + c) * NDH + d];
        sv += xv * Wv[((size_t)h * ND + c) * NDH + d];
    }
    part[0][q][d] = sk;
    part[1][q][d] = sv;
    __syncthreads();
    if (t < 64) {
        ks[t] = part[0][0][t] + part[0][1][t] + part[0][2][t] + part[0][3][t];
    } else if (t < 128) {
        int dd = t - 64;
        vsum[((size_t)b * NH + h) * NDH + dd] =
            part[1][0][dd] + part[1][1][dd] + part[1][2][dd] + part[1][3][dd];
    }
    __syncthreads();
    for (int c = t; c < ND; c += 256) {
        const float* wq = Wq + ((size_t)h * ND + c) * NDH;
        float s = 0.f;
        #pragma unroll 16
        for (int dd = 0; dd < NDH; ++dd) s += wq[dd] * ks[dd];
        wqk[((size_t)b * NH + h) * ND + c] = s * 0.125f;
    }
}

// ---------------- rowsum[b,h,t] = x[b,t,:] . wqk[b,h,:] ----------------
__global__ void rowsum_kernel(const float* __restrict__ x, const float* __restrict__ wqk,
                              float* __restrict__ rowsum) {
    int t = blockIdx.x, b = blockIdx.y;
    int tid = threadIdx.x;
    int wave = tid >> 6, lane = tid & 63;
    const float4 xv = ((const float4*)(x + ((size_t)b * NT + t) * ND))[tid];
    __shared__ float red[NH][4];
    for (int h = 0; h < NH; ++h) {
        const float4 wv = ((const float4*)(wqk + ((size_t)b * NH + h) * ND))[tid];
        float p = xv.x * wv.x + xv.y * wv.y + xv.z * wv.z + xv.w * wv.w;
        for (int off = 32; off; off >>= 1) p += __shfl_down(p, off, 64);
        if (lane == 0) red[h][wave] = p;
    }
    __syncthreads();
    if (tid < NH) {
        float s = red[tid][0] + red[tid][1] + red[tid][2] + red[tid][3];
        rowsum[((size_t)b * NH + tid) * NT + t] = s;
    }
}

// ---------------- softmax over t, in place ----------------
__global__ void softmax_kernel(float* __restrict__ rs) {
    int bh = blockIdx.x, tid = threadIdx.x;
    int wave = tid >> 6, lane = tid & 63;
    float* row = rs + (size_t)bh * NT;
    float4 v = ((float4*)row)[tid];
    float m = fmaxf(fmaxf(v.x, v.y), fmaxf(v.z, v.w));
    __shared__ float red[4];
    for (int off = 32; off; off >>= 1) m = fmaxf(m, __shfl_down(m, off, 64));
    if (lane == 0) red[wave] = m;
    __syncthreads();
    m = fmaxf(fmaxf(red[0], red[1]), fmaxf(red[2], red[3]));
    __syncthreads();
    float4 e;
    e.x = __expf(v.x - m); e.y = __expf(v.y - m);
    e.z = __expf(v.z - m); e.w = __expf(v.w - m);
    float s = e.x + e.y + e.z + e.w;
    for (int off = 32; off; off >>= 1) s += __shfl_down(s, off, 64);
    if (lane == 0) red[wave] = s;
    __syncthreads();
    s = red[0] + red[1] + red[2] + red[3];
    float inv = 1.f / s;
    e.x *= inv; e.y *= inv; e.z *= inv; e.w *= inv;
    ((float4*)row)[tid] = e;
}

// ---------------- LN1: x1 = LN(x + attn_out) -> bf16 ----------------
__global__ void ln1_kernel(const float* __restrict__ x, const float* __restrict__ p,
                           const float* __restrict__ vsum,
                           const float* __restrict__ g1, const float* __restrict__ b1,
                           __bf16* __restrict__ x1b) {
    int t = blockIdx.x, b = blockIdx.y, tid = threadIdx.x;
    int wave = tid >> 6, lane = tid & 63;
    size_t rowoff = ((size_t)b * NT + t) * ND;
    float4 xv = ((const float4*)(x + rowoff))[tid];
    int h = tid >> 4;  // c = tid*4 -> head = c/64
    float pv = p[((size_t)b * NH + h) * NT + t];
    float4 vs = ((const float4*)(vsum + ((size_t)b * NH + h) * NDH))[tid & 15];
    float4 s;
    s.x = xv.x + pv * vs.x; s.y = xv.y + pv * vs.y;
    s.z = xv.z + pv * vs.z; s.w = xv.w + pv * vs.w;
    float sum = s.x + s.y + s.z + s.w;
    float sq = s.x * s.x + s.y * s.y + s.z * s.z + s.w * s.w;
    __shared__ float rs_[4], rq_[4];
    for (int off = 32; off; off >>= 1) {
        sum += __shfl_down(sum, off, 64);
        sq += __shfl_down(sq, off, 64);
    }
    if (lane == 0) { rs_[wave] = sum; rq_[wave] = sq; }
    __syncthreads();
    sum = rs_[0] + rs_[1] + rs_[2] + rs_[3];
    sq = rq_[0] + rq_[1] + rq_[2] + rq_[3];
    float mu = sum * (1.f / ND);
    float var = sq * (1.f / ND) - mu * mu;
    float rstd = rsqrtf(var + LNEPS);
    float4 g = ((const float4*)g1)[tid];
    float4 bb = ((const float4*)b1)[tid];
    union { __bf16 h4[4]; uint2 u; } pk;
    pk.h4[0] = (__bf16)((s.x - mu) * rstd * g.x + bb.x);
    pk.h4[1] = (__bf16)((s.y - mu) * rstd * g.y + bb.y);
    pk.h4[2] = (__bf16)((s.z - mu) * rstd * g.z + bb.z);
    pk.h4[3] = (__bf16)((s.w - mu) * rstd * g.w + bb.w);
    ((uint2*)(x1b + rowoff))[tid] = pk.u;
}

// ---------------- bf16 MFMA GEMM: C = A(MxK) @ B(KxN), BT = B^T (NxK) ----------------
// MODE 0: relu, write bf16.  MODE 1: write f32.
template <int MODE>
__global__ __launch_bounds__(256) void gemm_bf16(const __bf16* __restrict__ A,
                                                 const __bf16* __restrict__ BT,
                                                 void* __restrict__ Cout) {
    const int K = 1024, N = 1024;
    __shared__ __bf16 As[128][40];
    __shared__ __bf16 Bs[128][40];
    int m0 = blockIdx.x * 128;
    int n0 = blockIdx.y * 128;
    int tid = threadIdx.x;
    int wid = tid >> 6, lane = tid & 63;
    int wr = wid >> 1, wc = wid & 1;
    int r = lane & 15, g = lane >> 4;
    int arow0 = tid >> 2;             // 0..63
    int akoff = (tid & 3) * 8;        // 0,8,16,24
    f32x4 acc[4][4] = {};
    for (int k0 = 0; k0 < K; k0 += 32) {
        uint4 a0 = *(const uint4*)(A + (size_t)(m0 + arow0) * K + k0 + akoff);
        uint4 a1 = *(const uint4*)(A + (size_t)(m0 + arow0 + 64) * K + k0 + akoff);
        uint4 b0 = *(const uint4*)(BT + (size_t)(n0 + arow0) * K + k0 + akoff);
        uint4 b1 = *(const uint4*)(BT + (size_t)(n0 + arow0 + 64) * K + k0 + akoff);
        __syncthreads();  // previous iter's LDS reads done
        *(uint4*)&As[arow0][akoff] = a0;
        *(uint4*)&As[arow0 + 64][akoff] = a1;
        *(uint4*)&Bs[arow0][akoff] = b0;
        *(uint4*)&Bs[arow0 + 64][akoff] = b1;
        __syncthreads();
        bf16x8 af[4], bf[4];
        #pragma unroll
        for (int mf = 0; mf < 4; ++mf)
            af[mf] = *(const bf16x8*)&As[wr * 64 + mf * 16 + r][g * 8];
        #pragma unroll
        for (int nf = 0; nf < 4; ++nf)
            bf[nf] = *(const bf16x8*)&Bs[wc * 64 + nf * 16 + r][g * 8];
        #pragma unroll
        for (int mf = 0; mf < 4; ++mf)
            #pragma unroll
            for (int nf = 0; nf < 4; ++nf)
                acc[mf][nf] = __builtin_amdgcn_mfma_f32_16x16x32_bf16(af[mf], bf[nf], acc[mf][nf], 0, 0, 0);
    }
    #pragma unroll
    for (int mf = 0; mf < 4; ++mf) {
        #pragma unroll
        for (int nf = 0; nf < 4; ++nf) {
            int col = n0 + wc * 64 + nf * 16 + r;
            #pragma unroll
            for (int i = 0; i < 4; ++i) {
                int row = m0 + wr * 64 + mf * 16 + g * 4 + i;
                float v = acc[mf][nf][i];
                if (MODE == 0) {
                    v = fmaxf(v, 0.f);
                    ((__bf16*)Cout)[(size_t)row * N + col] = (__bf16)v;
                } else {
                    ((float*)Cout)[(size_t)row * N + col] = v;
                }
            }
        }
    }
}

// ---------------- LN2: out = LN(x1 + ff) in place over d_out ----------------
__global__ void ln2_kernel(const __bf16* __restrict__ x1b, float* __restrict__ out,
                           const float* __restrict__ g2, const float* __restrict__ b2) {
    int t = blockIdx.x, b = blockIdx.y, tid = threadIdx.x;
    int wave = tid >> 6, lane = tid & 63;
    size_t rowoff = ((size_t)b * NT + t) * ND;
    union { __bf16 h4[4]; uint2 u; } pk;
    pk.u = ((const uint2*)(x1b + rowoff))[tid];
    float4 f = ((const float4*)(out + rowoff))[tid];
    float4 s;
    s.x = (float)pk.h4[0] + f.x; s.y = (float)pk.h4[1] + f.y;
    s.z = (float)pk.h4[2] + f.z; s.w = (float)pk.h4[3] + f.w;
    float sum = s.x + s.y + s.z + s.w;
    float sq = s.x * s.x + s.y * s.y + s.z * s.z + s.w * s.w;
    __shared__ float rs_[4], rq_[4];
    for (int off = 32; off; off >>= 1) {
        sum += __shfl_down(sum, off, 64);
        sq += __shfl_down(sq, off, 64);
    }
    if (lane == 0) { rs_[wave] = sum; rq_[wave] = sq; }
    __syncthreads();
    sum = rs_[0] + rs_[1] + rs_[2] + rs_[3];
    sq = rq_[0] + rq_[1] + rq_[2] + rq_[3];
    float mu = sum * (1.f / ND);
    float var = sq * (1.f / ND) - mu * mu;
    float rstd = rsqrtf(var + LNEPS);
    float4 g = ((const float4*)g2)[tid];
    float4 bb = ((const float4*)b2)[tid];
    float4 o;
    o.x = (s.x - mu) * rstd * g.x + bb.x;
    o.y = (s.y - mu) * rstd * g.y + bb.y;
    o.z = (s.z - mu) * rstd * g.z + bb.z;
    o.w = (s.w - mu) * rstd * g.w + bb.w;
    ((float4*)(out + rowoff))[tid] = o;
}

extern "C" void kernel_launch(void* const* d_in, const int* in_sizes, int n_in,
                              void* d_out, int out_size, void* d_ws, size_t ws_size,
                              hipStream_t stream) {
    const float* x  = (const float*)d_in[0];
    const float* Wq = (const float*)d_in[1];
    const float* Wk = (const float*)d_in[2];
    const float* Wv = (const float*)d_in[3];
    const float* W1 = (const float*)d_in[4];
    const float* W2 = (const float*)d_in[5];
    const float* g1 = (const float*)d_in[6];
    const float* b1 = (const float*)d_in[7];
    const float* g2 = (const float*)d_in[8];
    const float* b2 = (const float*)d_in[9];
    float* out = (float*)d_out;

    char* w = (char*)d_ws;
    float* xsum = (float*)w;   w += (size_t)NB * ND * 4;            // 32 KB
    float* vsum = (float*)w;   w += (size_t)NB * NH * NDH * 4;      // 32 KB
    float* wqk  = (float*)w;   w += (size_t)NB * NH * ND * 4;       // 512 KB
    float* rsum = (float*)w;   w += (size_t)NB * NH * NT * 4;       // 512 KB
    __bf16* x1b = (__bf16*)w;  w += (size_t)NM * ND * 2;            // 16 MB
    __bf16* h1b = (__bf16*)w;  w += (size_t)NM * ND * 2;            // 16 MB
    __bf16* w1t = (__bf16*)w;  w += (size_t)ND * ND * 2;            // 2 MB
    __bf16* w2t = (__bf16*)w;  w += (size_t)ND * ND * 2;            // 2 MB

    // weight transpose+convert (f32 KxN -> bf16 NxK)
    transpose_to_bf16<<<dim3(32, 32), dim3(32, 8), 0, stream>>>(W1, w1t);
    transpose_to_bf16<<<dim3(32, 32), dim3(32, 8), 0, stream>>>(W2, w2t);

    // attention (algebraically reduced)
    xsum_kernel<<<dim3(4, NB), 256, 0, stream>>>(x, xsum);
    head_prep<<<dim3(NH, NB), 256, 0, stream>>>(xsum, Wq, Wk, Wv, vsum, wqk);
    rowsum_kernel<<<dim3(NT, NB), 256, 0, stream>>>(x, wqk, rsum);
    softmax_kernel<<<NB * NH, 256, 0, stream>>>(rsum);
    ln1_kernel<<<dim3(NT, NB), 256, 0, stream>>>(x, rsum, vsum, g1, b1, x1b);

    // FFN
    gemm_bf16<0><<<dim3(64, 8), 256, 0, stream>>>(x1b, w1t, (void*)h1b);
    gemm_bf16<1><<<dim3(64, 8), 256, 0, stream>>>(h1b, w2t, (void*)out);
    ln2_kernel<<<dim3(NT, NB), 256, 0, stream>>>(x1b, out, g2, b2);
}

// Round 2
// 248.352 us; speedup vs baseline: 1.3081x; 1.3081x over previous
//
#include <hip/hip_runtime.h>

#define NB 8
#define NT 1024
#define ND 1024
#define NH 16
#define NDH 64
#define NM (NB*NT)   // 8192 rows
#define LNEPS 1e-5f

typedef __attribute__((ext_vector_type(8))) __bf16 bf16x8;
typedef __attribute__((ext_vector_type(4))) float f32x4;

// ---------------- W (K x N f32) -> WT (N x K bf16) ----------------
__global__ void transpose_to_bf16(const float* __restrict__ W, __bf16* __restrict__ WT) {
    __shared__ float tile[32][33];
    int bx = blockIdx.x * 32;  // n base
    int by = blockIdx.y * 32;  // k base
    int tx = threadIdx.x;      // 0..31
    int ty = threadIdx.y;      // 0..7
    for (int i = ty; i < 32; i += 8)
        tile[i][tx] = W[(size_t)(by + i) * ND + bx + tx];
    __syncthreads();
    for (int i = ty; i < 32; i += 8)
        WT[(size_t)(bx + i) * ND + by + tx] = (__bf16)tile[tx][i];
}

// ---------------- xsum[b,c] += partial sums over t ----------------
// grid (NB, 64): block handles 16 t-rows, 256 threads x float4 = 1024 channels
__global__ void xsum_kernel(const float* __restrict__ x, float* __restrict__ xsum) {
    int b = blockIdx.x;
    int chunk = blockIdx.y;
    int tid = threadIdx.x;
    const float4* xp = (const float4*)(x + ((size_t)b * NT + chunk * 16) * ND) + tid;
    float4 s = {0.f, 0.f, 0.f, 0.f};
    #pragma unroll
    for (int t = 0; t < 16; ++t) {
        float4 v = xp[(size_t)t * (ND / 4)];
        s.x += v.x; s.y += v.y; s.z += v.z; s.w += v.w;
    }
    float* dst = xsum + b * ND + tid * 4;
    atomicAdd(dst + 0, s.x);
    atomicAdd(dst + 1, s.y);
    atomicAdd(dst + 2, s.z);
    atomicAdd(dst + 3, s.w);
}

// ------- per (b,h): ksum,vsum = xsum@Wk/Wv ; wqk = (Wq@ksum)/8 -------
__global__ void head_prep(const float* __restrict__ xsum,
                          const float* __restrict__ Wq, const float* __restrict__ Wk,
                          const float* __restrict__ Wv,
                          float* __restrict__ vsum, float* __restrict__ wqk) {
    int h = blockIdx.x, b = blockIdx.y;
    int t = threadIdx.x;
    int d = t & 63, q = t >> 6;  // quarter 0..3
    __shared__ float part[2][4][NDH];
    __shared__ float ks[NDH];
    const float* xs = xsum + b * ND;
    float sk = 0.f, sv = 0.f;
    for (int c = q * 256; c < q * 256 + 256; ++c) {
        float xv = xs[c];
        sk += xv * Wk[((size_t)h * ND + c) * NDH + d];
        sv += xv * Wv[((size_t)h * ND + c) * NDH + d];
    }
    part[0][q][d] = sk;
    part[1][q][d] = sv;
    __syncthreads();
    if (t < 64) {
        ks[t] = part[0][0][t] + part[0][1][t] + part[0][2][t] + part[0][3][t];
    } else if (t < 128) {
        int dd = t - 64;
        vsum[((size_t)b * NH + h) * NDH + dd] =
            part[1][0][dd] + part[1][1][dd] + part[1][2][dd] + part[1][3][dd];
    }
    __syncthreads();
    for (int c = t; c < ND; c += 256) {
        const float* wq = Wq + ((size_t)h * ND + c) * NDH;
        float s = 0.f;
        #pragma unroll 16
        for (int dd = 0; dd < NDH; ++dd) s += wq[dd] * ks[dd];
        wqk[((size_t)b * NH + h) * ND + c] = s * 0.125f;
    }
}

// ---------------- rowsum[b,h,t] = x[b,t,:] . wqk[b,h,:] ----------------
// wave wid handles heads wid*4..+4; x row cached in regs
__global__ void rowsum_kernel(const float* __restrict__ x, const float* __restrict__ wqk,
                              float* __restrict__ rowsum) {
    int t = blockIdx.x, b = blockIdx.y;
    int tid = threadIdx.x, wid = tid >> 6, lane = tid & 63;
    const float4* xrow = (const float4*)(x + ((size_t)b * NT + t) * ND);
    float4 xv[4];
    #pragma unroll
    for (int c = 0; c < 4; ++c) xv[c] = xrow[c * 64 + lane];
    float acc[4];
    #pragma unroll
    for (int hh = 0; hh < 4; ++hh) {
        int h = wid * 4 + hh;
        const float4* wrow = (const float4*)(wqk + ((size_t)b * NH + h) * ND);
        float p = 0.f;
        #pragma unroll
        for (int c = 0; c < 4; ++c) {
            float4 wv = wrow[c * 64 + lane];
            p += xv[c].x * wv.x + xv[c].y * wv.y + xv[c].z * wv.z + xv[c].w * wv.w;
        }
        acc[hh] = p;
    }
    #pragma unroll
    for (int hh = 0; hh < 4; ++hh) {
        float p = acc[hh];
        for (int off = 32; off; off >>= 1) p += __shfl_down(p, off, 64);
        if (lane == 0) rowsum[((size_t)b * NH + wid * 4 + hh) * NT + t] = p;
    }
}

// ---------------- softmax over t, in place ----------------
__global__ void softmax_kernel(float* __restrict__ rs) {
    int bh = blockIdx.x, tid = threadIdx.x;
    int wave = tid >> 6, lane = tid & 63;
    float* row = rs + (size_t)bh * NT;
    float4 v = ((float4*)row)[tid];
    float m = fmaxf(fmaxf(v.x, v.y), fmaxf(v.z, v.w));
    __shared__ float red[4];
    for (int off = 32; off; off >>= 1) m = fmaxf(m, __shfl_down(m, off, 64));
    if (lane == 0) red[wave] = m;
    __syncthreads();
    m = fmaxf(fmaxf(red[0], red[1]), fmaxf(red[2], red[3]));
    __syncthreads();
    float4 e;
    e.x = __expf(v.x - m); e.y = __expf(v.y - m);
    e.z = __expf(v.z - m); e.w = __expf(v.w - m);
    float s = e.x + e.y + e.z + e.w;
    for (int off = 32; off; off >>= 1) s += __shfl_down(s, off, 64);
    if (lane == 0) red[wave] = s;
    __syncthreads();
    s = red[0] + red[1] + red[2] + red[3];
    float inv = 1.f / s;
    e.x *= inv; e.y *= inv; e.z *= inv; e.w *= inv;
    ((float4*)row)[tid] = e;
}

// ---------------- LN1: x1 = LN(x + attn_out) -> bf16 ----------------
__global__ void ln1_kernel(const float* __restrict__ x, const float* __restrict__ p,
                           const float* __restrict__ vsum,
                           const float* __restrict__ g1, const float* __restrict__ b1,
                           __bf16* __restrict__ x1b) {
    int t = blockIdx.x, b = blockIdx.y, tid = threadIdx.x;
    int wave = tid >> 6, lane = tid & 63;
    size_t rowoff = ((size_t)b * NT + t) * ND;
    float4 xv = ((const float4*)(x + rowoff))[tid];
    int h = tid >> 4;  // c = tid*4 -> head = c/64
    float pv = p[((size_t)b * NH + h) * NT + t];
    float4 vs = ((const float4*)(vsum + ((size_t)b * NH + h) * NDH))[tid & 15];
    float4 s;
    s.x = xv.x + pv * vs.x; s.y = xv.y + pv * vs.y;
    s.z = xv.z + pv * vs.z; s.w = xv.w + pv * vs.w;
    float sum = s.x + s.y + s.z + s.w;
    float sq = s.x * s.x + s.y * s.y + s.z * s.z + s.w * s.w;
    __shared__ float rs_[4], rq_[4];
    for (int off = 32; off; off >>= 1) {
        sum += __shfl_down(sum, off, 64);
        sq += __shfl_down(sq, off, 64);
    }
    if (lane == 0) { rs_[wave] = sum; rq_[wave] = sq; }
    __syncthreads();
    sum = rs_[0] + rs_[1] + rs_[2] + rs_[3];
    sq = rq_[0] + rq_[1] + rq_[2] + rq_[3];
    float mu = sum * (1.f / ND);
    float var = sq * (1.f / ND) - mu * mu;
    float rstd = rsqrtf(var + LNEPS);
    float4 g = ((const float4*)g1)[tid];
    float4 bb = ((const float4*)b1)[tid];
    union { __bf16 h4[4]; uint2 u; } pk;
    pk.h4[0] = (__bf16)((s.x - mu) * rstd * g.x + bb.x);
    pk.h4[1] = (__bf16)((s.y - mu) * rstd * g.y + bb.y);
    pk.h4[2] = (__bf16)((s.z - mu) * rstd * g.z + bb.z);
    pk.h4[3] = (__bf16)((s.w - mu) * rstd * g.w + bb.w);
    ((uint2*)(x1b + rowoff))[tid] = pk.u;
}

// ---------------- bf16 MFMA GEMM (m97 structure): C = A(MxK) @ B, BT = B^T (NxK) ----------------
// Linear LDS [128][32], global_load_lds width-16 staging.
// MODE 0: relu, write bf16.  MODE 1: write f32.
template <int MODE>
__global__ __launch_bounds__(256) void gemm_bf16(const __bf16* __restrict__ A,
                                                 const __bf16* __restrict__ BT,
                                                 void* __restrict__ Cout) {
    const int K = 1024, N = 1024;
    __shared__ __bf16 As[128][32];
    __shared__ __bf16 Bs[128][32];
    int m0 = blockIdx.x * 128;
    int n0 = blockIdx.y * 128;
    int tid = threadIdx.x;
    int wid = tid >> 6, lane = tid & 63;
    int wr = wid >> 1, wc = wid & 1;
    int r = lane & 15, g = lane >> 4;
    // staging: wave wid covers rows [wid*32, wid*32+32); lane l -> row wid*32 + l/4 (+16 for 2nd call),
    // k-offset (l&3)*8 elems. LDS dest = wave-uniform base + lane*16 (linear layout required).
    int srow = wid * 32 + (lane >> 2);
    int skoff = (lane & 3) * 8;
    const __bf16* Ag = A + (size_t)(m0 + srow) * K + skoff;
    const __bf16* Bg = BT + (size_t)(n0 + srow) * K + skoff;
    f32x4 acc[4][4] = {};
    for (int k0 = 0; k0 < K; k0 += 32) {
        __syncthreads();  // previous iter's LDS reads done
        __builtin_amdgcn_global_load_lds(
            (const __attribute__((address_space(1))) unsigned int*)(Ag + k0),
            (__attribute__((address_space(3))) unsigned int*)&As[wid * 32][0], 16, 0, 0);
        __builtin_amdgcn_global_load_lds(
            (const __attribute__((address_space(1))) unsigned int*)(Ag + (size_t)16 * K + k0),
            (__attribute__((address_space(3))) unsigned int*)&As[wid * 32 + 16][0], 16, 0, 0);
        __builtin_amdgcn_global_load_lds(
            (const __attribute__((address_space(1))) unsigned int*)(Bg + k0),
            (__attribute__((address_space(3))) unsigned int*)&Bs[wid * 32][0], 16, 0, 0);
        __builtin_amdgcn_global_load_lds(
            (const __attribute__((address_space(1))) unsigned int*)(Bg + (size_t)16 * K + k0),
            (__attribute__((address_space(3))) unsigned int*)&Bs[wid * 32 + 16][0], 16, 0, 0);
        __syncthreads();  // compiler drains vmcnt before barrier
        bf16x8 af[4], bf[4];
        #pragma unroll
        for (int mf = 0; mf < 4; ++mf)
            af[mf] = *(const bf16x8*)&As[wr * 64 + mf * 16 + r][g * 8];
        #pragma unroll
        for (int nf = 0; nf < 4; ++nf)
            bf[nf] = *(const bf16x8*)&Bs[wc * 64 + nf * 16 + r][g * 8];
        #pragma unroll
        for (int mf = 0; mf < 4; ++mf)
            #pragma unroll
            for (int nf = 0; nf < 4; ++nf)
                acc[mf][nf] = __builtin_amdgcn_mfma_f32_16x16x32_bf16(af[mf], bf[nf], acc[mf][nf], 0, 0, 0);
    }
    #pragma unroll
    for (int mf = 0; mf < 4; ++mf) {
        #pragma unroll
        for (int nf = 0; nf < 4; ++nf) {
            int col = n0 + wc * 64 + nf * 16 + r;
            #pragma unroll
            for (int i = 0; i < 4; ++i) {
                int row = m0 + wr * 64 + mf * 16 + g * 4 + i;
                float v = acc[mf][nf][i];
                if (MODE == 0) {
                    v = fmaxf(v, 0.f);
                    ((__bf16*)Cout)[(size_t)row * N + col] = (__bf16)v;
                } else {
                    ((float*)Cout)[(size_t)row * N + col] = v;
                }
            }
        }
    }
}

// ---------------- LN2: out = LN(x1 + ff) in place over d_out ----------------
__global__ void ln2_kernel(const __bf16* __restrict__ x1b, float* __restrict__ out,
                           const float* __restrict__ g2, const float* __restrict__ b2) {
    int t = blockIdx.x, b = blockIdx.y, tid = threadIdx.x;
    int wave = tid >> 6, lane = tid & 63;
    size_t rowoff = ((size_t)b * NT + t) * ND;
    union { __bf16 h4[4]; uint2 u; } pk;
    pk.u = ((const uint2*)(x1b + rowoff))[tid];
    float4 f = ((const float4*)(out + rowoff))[tid];
    float4 s;
    s.x = (float)pk.h4[0] + f.x; s.y = (float)pk.h4[1] + f.y;
    s.z = (float)pk.h4[2] + f.z; s.w = (float)pk.h4[3] + f.w;
    float sum = s.x + s.y + s.z + s.w;
    float sq = s.x * s.x + s.y * s.y + s.z * s.z + s.w * s.w;
    __shared__ float rs_[4], rq_[4];
    for (int off = 32; off; off >>= 1) {
        sum += __shfl_down(sum, off, 64);
        sq += __shfl_down(sq, off, 64);
    }
    if (lane == 0) { rs_[wave] = sum; rq_[wave] = sq; }
    __syncthreads();
    sum = rs_[0] + rs_[1] + rs_[2] + rs_[3];
    sq = rq_[0] + rq_[1] + rq_[2] + rq_[3];
    float mu = sum * (1.f / ND);
    float var = sq * (1.f / ND) - mu * mu;
    float rstd = rsqrtf(var + LNEPS);
    float4 g = ((const float4*)g2)[tid];
    float4 bb = ((const float4*)b2)[tid];
    float4 o;
    o.x = (s.x - mu) * rstd * g.x + bb.x;
    o.y = (s.y - mu) * rstd * g.y + bb.y;
    o.z = (s.z - mu) * rstd * g.z + bb.z;
    o.w = (s.w - mu) * rstd * g.w + bb.w;
    ((float4*)(out + rowoff))[tid] = o;
}

extern "C" void kernel_launch(void* const* d_in, const int* in_sizes, int n_in,
                              void* d_out, int out_size, void* d_ws, size_t ws_size,
                              hipStream_t stream) {
    const float* x  = (const float*)d_in[0];
    const float* Wq = (const float*)d_in[1];
    const float* Wk = (const float*)d_in[2];
    const float* Wv = (const float*)d_in[3];
    const float* W1 = (const float*)d_in[4];
    const float* W2 = (const float*)d_in[5];
    const float* g1 = (const float*)d_in[6];
    const float* b1 = (const float*)d_in[7];
    const float* g2 = (const float*)d_in[8];
    const float* b2 = (const float*)d_in[9];
    float* out = (float*)d_out;

    char* w = (char*)d_ws;
    float* xsum = (float*)w;   w += (size_t)NB * ND * 4;            // 32 KB
    float* vsum = (float*)w;   w += (size_t)NB * NH * NDH * 4;      // 32 KB
    float* wqk  = (float*)w;   w += (size_t)NB * NH * ND * 4;       // 512 KB
    float* rsum = (float*)w;   w += (size_t)NB * NH * NT * 4;       // 512 KB
    __bf16* x1b = (__bf16*)w;  w += (size_t)NM * ND * 2;            // 16 MB
    __bf16* h1b = (__bf16*)w;  w += (size_t)NM * ND * 2;            // 16 MB
    __bf16* w1t = (__bf16*)w;  w += (size_t)ND * ND * 2;            // 2 MB
    __bf16* w2t = (__bf16*)w;  w += (size_t)ND * ND * 2;            // 2 MB

    // zero xsum accumulator (ws is poisoned 0xAA before every launch)
    hipMemsetAsync(xsum, 0, (size_t)NB * ND * 4, stream);

    // weight transpose+convert (f32 KxN -> bf16 NxK)
    transpose_to_bf16<<<dim3(32, 32), dim3(32, 8), 0, stream>>>(W1, w1t);
    transpose_to_bf16<<<dim3(32, 32), dim3(32, 8), 0, stream>>>(W2, w2t);

    // attention (algebraically reduced)
    xsum_kernel<<<dim3(NB, 64), 256, 0, stream>>>(x, xsum);
    head_prep<<<dim3(NH, NB), 256, 0, stream>>>(xsum, Wq, Wk, Wv, vsum, wqk);
    rowsum_kernel<<<dim3(NT, NB), 256, 0, stream>>>(x, wqk, rsum);
    softmax_kernel<<<NB * NH, 256, 0, stream>>>(rsum);
    ln1_kernel<<<dim3(NT, NB), 256, 0, stream>>>(x, rsum, vsum, g1, b1, x1b);

    // FFN
    gemm_bf16<0><<<dim3(64, 8), 256, 0, stream>>>(x1b, w1t, (void*)h1b);
    gemm_bf16<1><<<dim3(64, 8), 256, 0, stream>>>(h1b, w2t, (void*)out);
    ln2_kernel<<<dim3(NT, NB), 256, 0, stream>>>(x1b, out, g2, b2);
}

// Round 3
// 235.732 us; speedup vs baseline: 1.3782x; 1.0535x over previous
//
#include <hip/hip_runtime.h>

#define NB 8
#define NT 1024
#define ND 1024
#define NH 16
#define NDH 64
#define NM (NB*NT)   // 8192 rows
#define LNEPS 1e-5f

typedef __attribute__((ext_vector_type(8))) __bf16 bf16x8;
typedef __attribute__((ext_vector_type(4))) float f32x4;

// ---------------- W (K x N f32) -> WT (N x K bf16), both W1 and W2 ----------------
__global__ void transpose_to_bf16(const float* __restrict__ W1, const float* __restrict__ W2,
                                  __bf16* __restrict__ WT1, __bf16* __restrict__ WT2) {
    __shared__ float tile[32][33];
    const float* W = blockIdx.z ? W2 : W1;
    __bf16* WT = blockIdx.z ? WT2 : WT1;
    int bx = blockIdx.x * 32;  // n base
    int by = blockIdx.y * 32;  // k base
    int tx = threadIdx.x;      // 0..31
    int ty = threadIdx.y;      // 0..7
    for (int i = ty; i < 32; i += 8)
        tile[i][tx] = W[(size_t)(by + i) * ND + bx + tx];
    __syncthreads();
    for (int i = ty; i < 32; i += 8)
        WT[(size_t)(bx + i) * ND + by + tx] = (__bf16)tile[tx][i];
}

// ---------------- xsum[b,c] += partial sums over t ----------------
__global__ void xsum_kernel(const float* __restrict__ x, float* __restrict__ xsum) {
    int b = blockIdx.x;
    int chunk = blockIdx.y;
    int tid = threadIdx.x;
    const float4* xp = (const float4*)(x + ((size_t)b * NT + chunk * 16) * ND) + tid;
    float4 s = {0.f, 0.f, 0.f, 0.f};
    #pragma unroll
    for (int t = 0; t < 16; ++t) {
        float4 v = xp[(size_t)t * (ND / 4)];
        s.x += v.x; s.y += v.y; s.z += v.z; s.w += v.w;
    }
    float* dst = xsum + b * ND + tid * 4;
    atomicAdd(dst + 0, s.x);
    atomicAdd(dst + 1, s.y);
    atomicAdd(dst + 2, s.z);
    atomicAdd(dst + 3, s.w);
}

// ------- per (b,h): ksum,vsum = xsum@Wk/Wv ; wqk = (Wq@ksum)/8 -------
__global__ void head_prep(const float* __restrict__ xsum,
                          const float* __restrict__ Wq, const float* __restrict__ Wk,
                          const float* __restrict__ Wv,
                          float* __restrict__ vsum, float* __restrict__ wqk) {
    int h = blockIdx.x, b = blockIdx.y;
    int t = threadIdx.x;
    int d = t & 63, q = t >> 6;  // quarter 0..3
    __shared__ float part[2][4][NDH];
    __shared__ float ks[NDH];
    const float* xs = xsum + b * ND;
    float sk = 0.f, sv = 0.f;
    for (int c = q * 256; c < q * 256 + 256; ++c) {
        float xv = xs[c];
        sk += xv * Wk[((size_t)h * ND + c) * NDH + d];
        sv += xv * Wv[((size_t)h * ND + c) * NDH + d];
    }
    part[0][q][d] = sk;
    part[1][q][d] = sv;
    __syncthreads();
    if (t < 64) {
        ks[t] = part[0][0][t] + part[0][1][t] + part[0][2][t] + part[0][3][t];
    } else if (t < 128) {
        int dd = t - 64;
        vsum[((size_t)b * NH + h) * NDH + dd] =
            part[1][0][dd] + part[1][1][dd] + part[1][2][dd] + part[1][3][dd];
    }
    __syncthreads();
    for (int c = t; c < ND; c += 256) {
        const float* wq = Wq + ((size_t)h * ND + c) * NDH;
        float s = 0.f;
        #pragma unroll 16
        for (int dd = 0; dd < NDH; ++dd) s += wq[dd] * ks[dd];
        wqk[((size_t)b * NH + h) * ND + c] = s * 0.125f;
    }
}

// ---------------- rowsum[b,h,t] = x[b,t,:] . wqk[b,h,:] ----------------
// block = (16-t chunk, b); wqk[b] staged in LDS once; wave w handles 4 t's.
__global__ __launch_bounds__(256) void rowsum_kernel(const float* __restrict__ x,
                                                     const float* __restrict__ wqk,
                                                     float* __restrict__ rowsum) {
    __shared__ float wl[NH * ND];  // 64 KB
    int tc = blockIdx.x, b = blockIdx.y;
    int tid = threadIdx.x, wid = tid >> 6, lane = tid & 63;
    {
        const float4* wsrc = (const float4*)(wqk + (size_t)b * NH * ND);
        float4* wdst = (float4*)wl;
        #pragma unroll
        for (int i = 0; i < 16; ++i) wdst[tid + i * 256] = wsrc[tid + i * 256];
    }
    __syncthreads();
    const float4* wl4 = (const float4*)wl;
    #pragma unroll
    for (int j = 0; j < 4; ++j) {
        int t = tc * 16 + wid * 4 + j;
        const float4* xrow = (const float4*)(x + ((size_t)b * NT + t) * ND);
        float4 xv[4];
        #pragma unroll
        for (int c = 0; c < 4; ++c) xv[c] = xrow[c * 64 + lane];
        #pragma unroll
        for (int h = 0; h < NH; ++h) {
            float p = 0.f;
            #pragma unroll
            for (int c = 0; c < 4; ++c) {
                float4 wv = wl4[h * 256 + c * 64 + lane];
                p += xv[c].x * wv.x + xv[c].y * wv.y + xv[c].z * wv.z + xv[c].w * wv.w;
            }
            for (int off = 32; off; off >>= 1) p += __shfl_down(p, off, 64);
            if (lane == 0) rowsum[((size_t)b * NH + h) * NT + t] = p;
        }
    }
}

// ---------------- softmax over t, in place ----------------
__global__ void softmax_kernel(float* __restrict__ rs) {
    int bh = blockIdx.x, tid = threadIdx.x;
    int wave = tid >> 6, lane = tid & 63;
    float* row = rs + (size_t)bh * NT;
    float4 v = ((float4*)row)[tid];
    float m = fmaxf(fmaxf(v.x, v.y), fmaxf(v.z, v.w));
    __shared__ float red[4];
    for (int off = 32; off; off >>= 1) m = fmaxf(m, __shfl_down(m, off, 64));
    if (lane == 0) red[wave] = m;
    __syncthreads();
    m = fmaxf(fmaxf(red[0], red[1]), fmaxf(red[2], red[3]));
    __syncthreads();
    float4 e;
    e.x = __expf(v.x - m); e.y = __expf(v.y - m);
    e.z = __expf(v.z - m); e.w = __expf(v.w - m);
    float s = e.x + e.y + e.z + e.w;
    for (int off = 32; off; off >>= 1) s += __shfl_down(s, off, 64);
    if (lane == 0) red[wave] = s;
    __syncthreads();
    s = red[0] + red[1] + red[2] + red[3];
    float inv = 1.f / s;
    e.x *= inv; e.y *= inv; e.z *= inv; e.w *= inv;
    ((float4*)row)[tid] = e;
}

// ---------------- LN1: x1 = LN(x + attn_out) -> bf16 ----------------
__global__ void ln1_kernel(const float* __restrict__ x, const float* __restrict__ p,
                           const float* __restrict__ vsum,
                           const float* __restrict__ g1, const float* __restrict__ b1,
                           __bf16* __restrict__ x1b) {
    int t = blockIdx.x, b = blockIdx.y, tid = threadIdx.x;
    int wave = tid >> 6, lane = tid & 63;
    size_t rowoff = ((size_t)b * NT + t) * ND;
    float4 xv = ((const float4*)(x + rowoff))[tid];
    int h = tid >> 4;  // c = tid*4 -> head = c/64
    float pv = p[((size_t)b * NH + h) * NT + t];
    float4 vs = ((const float4*)(vsum + ((size_t)b * NH + h) * NDH))[tid & 15];
    float4 s;
    s.x = xv.x + pv * vs.x; s.y = xv.y + pv * vs.y;
    s.z = xv.z + pv * vs.z; s.w = xv.w + pv * vs.w;
    float sum = s.x + s.y + s.z + s.w;
    float sq = s.x * s.x + s.y * s.y + s.z * s.z + s.w * s.w;
    __shared__ float rs_[4], rq_[4];
    for (int off = 32; off; off >>= 1) {
        sum += __shfl_down(sum, off, 64);
        sq += __shfl_down(sq, off, 64);
    }
    if (lane == 0) { rs_[wave] = sum; rq_[wave] = sq; }
    __syncthreads();
    sum = rs_[0] + rs_[1] + rs_[2] + rs_[3];
    sq = rq_[0] + rq_[1] + rq_[2] + rq_[3];
    float mu = sum * (1.f / ND);
    float var = sq * (1.f / ND) - mu * mu;
    float rstd = rsqrtf(var + LNEPS);
    float4 g = ((const float4*)g1)[tid];
    float4 bb = ((const float4*)b1)[tid];
    union { __bf16 h4[4]; uint2 u; } pk;
    pk.h4[0] = (__bf16)((s.x - mu) * rstd * g.x + bb.x);
    pk.h4[1] = (__bf16)((s.y - mu) * rstd * g.y + bb.y);
    pk.h4[2] = (__bf16)((s.z - mu) * rstd * g.z + bb.z);
    pk.h4[3] = (__bf16)((s.w - mu) * rstd * g.w + bb.w);
    ((uint2*)(x1b + rowoff))[tid] = pk.u;
}

// ---------------- bf16 MFMA GEMM (m97 structure + XCD swizzle) ----------------
// C = A(8192xK) @ B, BT = B^T (NxK). Writes bf16. RELU=1 applies relu.
// 1D grid 512 blocks: XCD-bijective swizzle (512 % 8 == 0).
template <int RELU>
__global__ __launch_bounds__(256) void gemm_bf16(const __bf16* __restrict__ A,
                                                 const __bf16* __restrict__ BT,
                                                 __bf16* __restrict__ Cout) {
    const int K = 1024, N = 1024;
    __shared__ __bf16 As[128][32];
    __shared__ __bf16 Bs[128][32];
    int raw = blockIdx.x;
    int swz = (raw & 7) * 64 + (raw >> 3);   // XCD k owns swz in [k*64, k*64+64)
    int m0 = (swz >> 3) * 128;               // 8 m-panels per XCD
    int n0 = (swz & 7) * 128;                // all 8 n-panels (B L2-resident)
    int tid = threadIdx.x;
    int wid = tid >> 6, lane = tid & 63;
    int wr = wid >> 1, wc = wid & 1;
    int r = lane & 15, g = lane >> 4;
    int srow = wid * 32 + (lane >> 2);
    int skoff = (lane & 3) * 8;
    const __bf16* Ag = A + (size_t)(m0 + srow) * K + skoff;
    const __bf16* Bg = BT + (size_t)(n0 + srow) * K + skoff;
    f32x4 acc[4][4] = {};
    for (int k0 = 0; k0 < K; k0 += 32) {
        __syncthreads();  // previous iter's LDS reads done
        __builtin_amdgcn_global_load_lds(
            (const __attribute__((address_space(1))) unsigned int*)(Ag + k0),
            (__attribute__((address_space(3))) unsigned int*)&As[wid * 32][0], 16, 0, 0);
        __builtin_amdgcn_global_load_lds(
            (const __attribute__((address_space(1))) unsigned int*)(Ag + (size_t)16 * K + k0),
            (__attribute__((address_space(3))) unsigned int*)&As[wid * 32 + 16][0], 16, 0, 0);
        __builtin_amdgcn_global_load_lds(
            (const __attribute__((address_space(1))) unsigned int*)(Bg + k0),
            (__attribute__((address_space(3))) unsigned int*)&Bs[wid * 32][0], 16, 0, 0);
        __builtin_amdgcn_global_load_lds(
            (const __attribute__((address_space(1))) unsigned int*)(Bg + (size_t)16 * K + k0),
            (__attribute__((address_space(3))) unsigned int*)&Bs[wid * 32 + 16][0], 16, 0, 0);
        __syncthreads();  // compiler drains vmcnt before barrier
        bf16x8 af[4], bf[4];
        #pragma unroll
        for (int mf = 0; mf < 4; ++mf)
            af[mf] = *(const bf16x8*)&As[wr * 64 + mf * 16 + r][g * 8];
        #pragma unroll
        for (int nf = 0; nf < 4; ++nf)
            bf[nf] = *(const bf16x8*)&Bs[wc * 64 + nf * 16 + r][g * 8];
        #pragma unroll
        for (int mf = 0; mf < 4; ++mf)
            #pragma unroll
            for (int nf = 0; nf < 4; ++nf)
                acc[mf][nf] = __builtin_amdgcn_mfma_f32_16x16x32_bf16(af[mf], bf[nf], acc[mf][nf], 0, 0, 0);
    }
    #pragma unroll
    for (int mf = 0; mf < 4; ++mf) {
        #pragma unroll
        for (int nf = 0; nf < 4; ++nf) {
            int col = n0 + wc * 64 + nf * 16 + r;
            #pragma unroll
            for (int i = 0; i < 4; ++i) {
                int row = m0 + wr * 64 + mf * 16 + g * 4 + i;
                float v = acc[mf][nf][i];
                if (RELU) v = fmaxf(v, 0.f);
                Cout[(size_t)row * N + col] = (__bf16)v;
            }
        }
    }
}

// ---------------- LN2: out = LN(x1 + ff) -> f32 ----------------
__global__ void ln2_kernel(const __bf16* __restrict__ x1b, const __bf16* __restrict__ ffb,
                           float* __restrict__ out,
                           const float* __restrict__ g2, const float* __restrict__ b2) {
    int t = blockIdx.x, b = blockIdx.y, tid = threadIdx.x;
    int wave = tid >> 6, lane = tid & 63;
    size_t rowoff = ((size_t)b * NT + t) * ND;
    union { __bf16 h4[4]; uint2 u; } pk, pf;
    pk.u = ((const uint2*)(x1b + rowoff))[tid];
    pf.u = ((const uint2*)(ffb + rowoff))[tid];
    float4 s;
    s.x = (float)pk.h4[0] + (float)pf.h4[0];
    s.y = (float)pk.h4[1] + (float)pf.h4[1];
    s.z = (float)pk.h4[2] + (float)pf.h4[2];
    s.w = (float)pk.h4[3] + (float)pf.h4[3];
    float sum = s.x + s.y + s.z + s.w;
    float sq = s.x * s.x + s.y * s.y + s.z * s.z + s.w * s.w;
    __shared__ float rs_[4], rq_[4];
    for (int off = 32; off; off >>= 1) {
        sum += __shfl_down(sum, off, 64);
        sq += __shfl_down(sq, off, 64);
    }
    if (lane == 0) { rs_[wave] = sum; rq_[wave] = sq; }
    __syncthreads();
    sum = rs_[0] + rs_[1] + rs_[2] + rs_[3];
    sq = rq_[0] + rq_[1] + rq_[2] + rq_[3];
    float mu = sum * (1.f / ND);
    float var = sq * (1.f / ND) - mu * mu;
    float rstd = rsqrtf(var + LNEPS);
    float4 g = ((const float4*)g2)[tid];
    float4 bb = ((const float4*)b2)[tid];
    float4 o;
    o.x = (s.x - mu) * rstd * g.x + bb.x;
    o.y = (s.y - mu) * rstd * g.y + bb.y;
    o.z = (s.z - mu) * rstd * g.z + bb.z;
    o.w = (s.w - mu) * rstd * g.w + bb.w;
    ((float4*)(out + rowoff))[tid] = o;
}

extern "C" void kernel_launch(void* const* d_in, const int* in_sizes, int n_in,
                              void* d_out, int out_size, void* d_ws, size_t ws_size,
                              hipStream_t stream) {
    const float* x  = (const float*)d_in[0];
    const float* Wq = (const float*)d_in[1];
    const float* Wk = (const float*)d_in[2];
    const float* Wv = (const float*)d_in[3];
    const float* W1 = (const float*)d_in[4];
    const float* W2 = (const float*)d_in[5];
    const float* g1 = (const float*)d_in[6];
    const float* b1 = (const float*)d_in[7];
    const float* g2 = (const float*)d_in[8];
    const float* b2 = (const float*)d_in[9];
    float* out = (float*)d_out;

    char* w = (char*)d_ws;
    float* xsum = (float*)w;   w += (size_t)NB * ND * 4;            // 32 KB
    float* vsum = (float*)w;   w += (size_t)NB * NH * NDH * 4;      // 32 KB
    float* wqk  = (float*)w;   w += (size_t)NB * NH * ND * 4;       // 512 KB
    float* rsum = (float*)w;   w += (size_t)NB * NH * NT * 4;       // 512 KB
    __bf16* x1b = (__bf16*)w;  w += (size_t)NM * ND * 2;            // 16 MB
    __bf16* h1b = (__bf16*)w;  w += (size_t)NM * ND * 2;            // 16 MB
    __bf16* ffb = (__bf16*)w;  w += (size_t)NM * ND * 2;            // 16 MB
    __bf16* w1t = (__bf16*)w;  w += (size_t)ND * ND * 2;            // 2 MB
    __bf16* w2t = (__bf16*)w;  w += (size_t)ND * ND * 2;            // 2 MB

    // zero xsum accumulator (ws is poisoned 0xAA before every launch)
    hipMemsetAsync(xsum, 0, (size_t)NB * ND * 4, stream);

    // weight transpose+convert (f32 KxN -> bf16 NxK), W1 and W2 in one dispatch
    transpose_to_bf16<<<dim3(32, 32, 2), dim3(32, 8), 0, stream>>>(W1, W2, w1t, w2t);

    // attention (algebraically reduced)
    xsum_kernel<<<dim3(NB, 64), 256, 0, stream>>>(x, xsum);
    head_prep<<<dim3(NH, NB), 256, 0, stream>>>(xsum, Wq, Wk, Wv, vsum, wqk);
    rowsum_kernel<<<dim3(64, NB), 256, 0, stream>>>(x, wqk, rsum);
    softmax_kernel<<<NB * NH, 256, 0, stream>>>(rsum);
    ln1_kernel<<<dim3(NT, NB), 256, 0, stream>>>(x, rsum, vsum, g1, b1, x1b);

    // FFN
    gemm_bf16<1><<<512, 256, 0, stream>>>(x1b, w1t, h1b);
    gemm_bf16<0><<<512, 256, 0, stream>>>(h1b, w2t, ffb);
    ln2_kernel<<<dim3(NT, NB), 256, 0, stream>>>(x1b, ffb, out, g2, b2);
}

// Round 4
// 232.795 us; speedup vs baseline: 1.3956x; 1.0126x over previous
//
#include <hip/hip_runtime.h>

#define NB 8
#define NT 1024
#define ND 1024
#define NH 16
#define NDH 64
#define NM (NB*NT)   // 8192 rows
#define LNEPS 1e-5f

typedef __attribute__((ext_vector_type(8))) __bf16 bf16x8;
typedef __attribute__((ext_vector_type(4))) float f32x4;

// ---------------- W (K x N f32) -> WT (N x K bf16), both W1 and W2 ----------------
__global__ void transpose_to_bf16(const float* __restrict__ W1, const float* __restrict__ W2,
                                  __bf16* __restrict__ WT1, __bf16* __restrict__ WT2) {
    __shared__ float tile[32][33];
    const float* W = blockIdx.z ? W2 : W1;
    __bf16* WT = blockIdx.z ? WT2 : WT1;
    int bx = blockIdx.x * 32;  // n base
    int by = blockIdx.y * 32;  // k base
    int tx = threadIdx.x;      // 0..31
    int ty = threadIdx.y;      // 0..7
    for (int i = ty; i < 32; i += 8)
        tile[i][tx] = W[(size_t)(by + i) * ND + bx + tx];
    __syncthreads();
    for (int i = ty; i < 32; i += 8)
        WT[(size_t)(bx + i) * ND + by + tx] = (__bf16)tile[tx][i];
}

// ---------------- xsum[b,c] += partial sums over t ----------------
__global__ void xsum_kernel(const float* __restrict__ x, float* __restrict__ xsum) {
    int b = blockIdx.x;
    int chunk = blockIdx.y;
    int tid = threadIdx.x;
    const float4* xp = (const float4*)(x + ((size_t)b * NT + chunk * 16) * ND) + tid;
    float4 s = {0.f, 0.f, 0.f, 0.f};
    #pragma unroll
    for (int t = 0; t < 16; ++t) {
        float4 v = xp[(size_t)t * (ND / 4)];
        s.x += v.x; s.y += v.y; s.z += v.z; s.w += v.w;
    }
    float* dst = xsum + b * ND + tid * 4;
    atomicAdd(dst + 0, s.x);
    atomicAdd(dst + 1, s.y);
    atomicAdd(dst + 2, s.z);
    atomicAdd(dst + 3, s.w);
}

// ------- per (b,h): ksum,vsum = xsum@Wk/Wv ; wqk = (Wq@ksum)/8 -------
__global__ void head_prep(const float* __restrict__ xsum,
                          const float* __restrict__ Wq, const float* __restrict__ Wk,
                          const float* __restrict__ Wv,
                          float* __restrict__ vsum, float* __restrict__ wqk) {
    int h = blockIdx.x, b = blockIdx.y;
    int t = threadIdx.x;
    int d = t & 63, q = t >> 6;  // quarter 0..3
    __shared__ float part[2][4][NDH];
    __shared__ float ks[NDH];
    const float* xs = xsum + b * ND;
    float sk = 0.f, sv = 0.f;
    for (int c = q * 256; c < q * 256 + 256; ++c) {
        float xv = xs[c];
        sk += xv * Wk[((size_t)h * ND + c) * NDH + d];
        sv += xv * Wv[((size_t)h * ND + c) * NDH + d];
    }
    part[0][q][d] = sk;
    part[1][q][d] = sv;
    __syncthreads();
    if (t < 64) {
        ks[t] = part[0][0][t] + part[0][1][t] + part[0][2][t] + part[0][3][t];
    } else if (t < 128) {
        int dd = t - 64;
        vsum[((size_t)b * NH + h) * NDH + dd] =
            part[1][0][dd] + part[1][1][dd] + part[1][2][dd] + part[1][3][dd];
    }
    __syncthreads();
    for (int c = t; c < ND; c += 256) {
        const float* wq = Wq + ((size_t)h * ND + c) * NDH;
        float s = 0.f;
        #pragma unroll 16
        for (int dd = 0; dd < NDH; ++dd) s += wq[dd] * ks[dd];
        wqk[((size_t)b * NH + h) * ND + c] = s * 0.125f;
    }
}

// ---------------- rowsum[b,h,t] = x[b,t,:] . wqk[b,h,:] ----------------
// Wave handles 4 consecutive t; acc[4][16] in regs; wqk from L2 (coalesced, reused x4);
// 17-shfl multi-head butterfly reduce; float4 store per head.
__global__ __launch_bounds__(256) void rowsum_kernel(const float* __restrict__ x,
                                                     const float* __restrict__ wqk,
                                                     float* __restrict__ rowsum) {
    int tc = blockIdx.x, b = blockIdx.y;
    int tid = threadIdx.x, wid = tid >> 6, lane = tid & 63;
    int t0 = tc * 16 + wid * 4;
    float acc[4][16];
    #pragma unroll
    for (int tq = 0; tq < 4; ++tq)
        #pragma unroll
        for (int h = 0; h < 16; ++h) acc[tq][h] = 0.f;
    const float4* wb = (const float4*)(wqk + (size_t)b * NH * ND);
    #pragma unroll
    for (int chunk = 0; chunk < 4; ++chunk) {
        float4 xv[4];
        #pragma unroll
        for (int tq = 0; tq < 4; ++tq)
            xv[tq] = ((const float4*)(x + ((size_t)b * NT + t0 + tq) * ND))[chunk * 64 + lane];
        #pragma unroll
        for (int h = 0; h < 16; ++h) {
            float4 wv = wb[h * 256 + chunk * 64 + lane];
            #pragma unroll
            for (int tq = 0; tq < 4; ++tq)
                acc[tq][h] += xv[tq].x * wv.x + xv[tq].y * wv.y +
                              xv[tq].z * wv.z + xv[tq].w * wv.w;
        }
    }
    // butterfly: 16 head-sums over 64 lanes; lane ends with head (lane&15)
    bool c0 = lane & 1, c1 = lane & 2, c2 = lane & 4, c3 = lane & 8;
    float out4[4];
    #pragma unroll
    for (int tq = 0; tq < 4; ++tq) {
        float w8[8];
        #pragma unroll
        for (int j = 0; j < 8; ++j) {
            float send = c0 ? acc[tq][2 * j] : acc[tq][2 * j + 1];
            float recv = __shfl_xor(send, 1, 64);
            w8[j] = (c0 ? acc[tq][2 * j + 1] : acc[tq][2 * j]) + recv;
        }
        float u4[4];
        #pragma unroll
        for (int j = 0; j < 4; ++j) {
            float send = c1 ? w8[2 * j] : w8[2 * j + 1];
            float recv = __shfl_xor(send, 2, 64);
            u4[j] = (c1 ? w8[2 * j + 1] : w8[2 * j]) + recv;
        }
        float s2[2];
        #pragma unroll
        for (int j = 0; j < 2; ++j) {
            float send = c2 ? u4[2 * j] : u4[2 * j + 1];
            float recv = __shfl_xor(send, 4, 64);
            s2[j] = (c2 ? u4[2 * j + 1] : u4[2 * j]) + recv;
        }
        float send = c3 ? s2[0] : s2[1];
        float recv = __shfl_xor(send, 8, 64);
        float r = (c3 ? s2[1] : s2[0]) + recv;
        r += __shfl_xor(r, 16, 64);
        r += __shfl_xor(r, 32, 64);
        out4[tq] = r;
    }
    if (lane < 16) {
        float4 o = {out4[0], out4[1], out4[2], out4[3]};
        *(float4*)(rowsum + ((size_t)b * NH + lane) * NT + t0) = o;
    }
}

// ---------------- softmax over t, in place ----------------
__global__ void softmax_kernel(float* __restrict__ rs) {
    int bh = blockIdx.x, tid = threadIdx.x;
    int wave = tid >> 6, lane = tid & 63;
    float* row = rs + (size_t)bh * NT;
    float4 v = ((float4*)row)[tid];
    float m = fmaxf(fmaxf(v.x, v.y), fmaxf(v.z, v.w));
    __shared__ float red[4];
    for (int off = 32; off; off >>= 1) m = fmaxf(m, __shfl_down(m, off, 64));
    if (lane == 0) red[wave] = m;
    __syncthreads();
    m = fmaxf(fmaxf(red[0], red[1]), fmaxf(red[2], red[3]));
    __syncthreads();
    float4 e;
    e.x = __expf(v.x - m); e.y = __expf(v.y - m);
    e.z = __expf(v.z - m); e.w = __expf(v.w - m);
    float s = e.x + e.y + e.z + e.w;
    for (int off = 32; off; off >>= 1) s += __shfl_down(s, off, 64);
    if (lane == 0) red[wave] = s;
    __syncthreads();
    s = red[0] + red[1] + red[2] + red[3];
    float inv = 1.f / s;
    e.x *= inv; e.y *= inv; e.z *= inv; e.w *= inv;
    ((float4*)row)[tid] = e;
}

// ---------------- LN1: x1 = LN(x + attn_out) -> bf16 ----------------
__global__ void ln1_kernel(const float* __restrict__ x, const float* __restrict__ p,
                           const float* __restrict__ vsum,
                           const float* __restrict__ g1, const float* __restrict__ b1,
                           __bf16* __restrict__ x1b) {
    int t = blockIdx.x, b = blockIdx.y, tid = threadIdx.x;
    int wave = tid >> 6, lane = tid & 63;
    size_t rowoff = ((size_t)b * NT + t) * ND;
    float4 xv = ((const float4*)(x + rowoff))[tid];
    int h = tid >> 4;  // c = tid*4 -> head = c/64
    float pv = p[((size_t)b * NH + h) * NT + t];
    float4 vs = ((const float4*)(vsum + ((size_t)b * NH + h) * NDH))[tid & 15];
    float4 s;
    s.x = xv.x + pv * vs.x; s.y = xv.y + pv * vs.y;
    s.z = xv.z + pv * vs.z; s.w = xv.w + pv * vs.w;
    float sum = s.x + s.y + s.z + s.w;
    float sq = s.x * s.x + s.y * s.y + s.z * s.z + s.w * s.w;
    __shared__ float rs_[4], rq_[4];
    for (int off = 32; off; off >>= 1) {
        sum += __shfl_down(sum, off, 64);
        sq += __shfl_down(sq, off, 64);
    }
    if (lane == 0) { rs_[wave] = sum; rq_[wave] = sq; }
    __syncthreads();
    sum = rs_[0] + rs_[1] + rs_[2] + rs_[3];
    sq = rq_[0] + rq_[1] + rq_[2] + rq_[3];
    float mu = sum * (1.f / ND);
    float var = sq * (1.f / ND) - mu * mu;
    float rstd = rsqrtf(var + LNEPS);
    float4 g = ((const float4*)g1)[tid];
    float4 bb = ((const float4*)b1)[tid];
    union { __bf16 h4[4]; uint2 u; } pk;
    pk.h4[0] = (__bf16)((s.x - mu) * rstd * g.x + bb.x);
    pk.h4[1] = (__bf16)((s.y - mu) * rstd * g.y + bb.y);
    pk.h4[2] = (__bf16)((s.z - mu) * rstd * g.z + bb.z);
    pk.h4[3] = (__bf16)((s.w - mu) * rstd * g.w + bb.w);
    ((uint2*)(x1b + rowoff))[tid] = pk.u;
}

// ---------------- bf16 MFMA GEMM (m97 structure + XCD swizzle) ----------------
// C = A(8192xK) @ B, BT = B^T (NxK). Writes bf16. RELU=1 applies relu.
// 1D grid 512 blocks: XCD-bijective swizzle (512 % 8 == 0).
template <int RELU>
__global__ __launch_bounds__(256) void gemm_bf16(const __bf16* __restrict__ A,
                                                 const __bf16* __restrict__ BT,
                                                 __bf16* __restrict__ Cout) {
    const int K = 1024, N = 1024;
    __shared__ __bf16 As[128][32];
    __shared__ __bf16 Bs[128][32];
    int raw = blockIdx.x;
    int swz = (raw & 7) * 64 + (raw >> 3);   // XCD k owns swz in [k*64, k*64+64)
    int m0 = (swz >> 3) * 128;               // 8 m-panels per XCD
    int n0 = (swz & 7) * 128;                // all 8 n-panels (B L2-resident)
    int tid = threadIdx.x;
    int wid = tid >> 6, lane = tid & 63;
    int wr = wid >> 1, wc = wid & 1;
    int r = lane & 15, g = lane >> 4;
    int srow = wid * 32 + (lane >> 2);
    int skoff = (lane & 3) * 8;
    const __bf16* Ag = A + (size_t)(m0 + srow) * K + skoff;
    const __bf16* Bg = BT + (size_t)(n0 + srow) * K + skoff;
    f32x4 acc[4][4] = {};
    for (int k0 = 0; k0 < K; k0 += 32) {
        __syncthreads();  // previous iter's LDS reads done
        __builtin_amdgcn_global_load_lds(
            (const __attribute__((address_space(1))) unsigned int*)(Ag + k0),
            (__attribute__((address_space(3))) unsigned int*)&As[wid * 32][0], 16, 0, 0);
        __builtin_amdgcn_global_load_lds(
            (const __attribute__((address_space(1))) unsigned int*)(Ag + (size_t)16 * K + k0),
            (__attribute__((address_space(3))) unsigned int*)&As[wid * 32 + 16][0], 16, 0, 0);
        __builtin_amdgcn_global_load_lds(
            (const __attribute__((address_space(1))) unsigned int*)(Bg + k0),
            (__attribute__((address_space(3))) unsigned int*)&Bs[wid * 32][0], 16, 0, 0);
        __builtin_amdgcn_global_load_lds(
            (const __attribute__((address_space(1))) unsigned int*)(Bg + (size_t)16 * K + k0),
            (__attribute__((address_space(3))) unsigned int*)&Bs[wid * 32 + 16][0], 16, 0, 0);
        __syncthreads();  // compiler drains vmcnt before barrier
        bf16x8 af[4], bf[4];
        #pragma unroll
        for (int mf = 0; mf < 4; ++mf)
            af[mf] = *(const bf16x8*)&As[wr * 64 + mf * 16 + r][g * 8];
        #pragma unroll
        for (int nf = 0; nf < 4; ++nf)
            bf[nf] = *(const bf16x8*)&Bs[wc * 64 + nf * 16 + r][g * 8];
        #pragma unroll
        for (int mf = 0; mf < 4; ++mf)
            #pragma unroll
            for (int nf = 0; nf < 4; ++nf)
                acc[mf][nf] = __builtin_amdgcn_mfma_f32_16x16x32_bf16(af[mf], bf[nf], acc[mf][nf], 0, 0, 0);
    }
    #pragma unroll
    for (int mf = 0; mf < 4; ++mf) {
        #pragma unroll
        for (int nf = 0; nf < 4; ++nf) {
            int col = n0 + wc * 64 + nf * 16 + r;
            #pragma unroll
            for (int i = 0; i < 4; ++i) {
                int row = m0 + wr * 64 + mf * 16 + g * 4 + i;
                float v = acc[mf][nf][i];
                if (RELU) v = fmaxf(v, 0.f);
                Cout[(size_t)row * N + col] = (__bf16)v;
            }
        }
    }
}

// ---------------- LN2: out = LN(x1 + ff) -> f32 ----------------
__global__ void ln2_kernel(const __bf16* __restrict__ x1b, const __bf16* __restrict__ ffb,
                           float* __restrict__ out,
                           const float* __restrict__ g2, const float* __restrict__ b2) {
    int t = blockIdx.x, b = blockIdx.y, tid = threadIdx.x;
    int wave = tid >> 6, lane = tid & 63;
    size_t rowoff = ((size_t)b * NT + t) * ND;
    union { __bf16 h4[4]; uint2 u; } pk, pf;
    pk.u = ((const uint2*)(x1b + rowoff))[tid];
    pf.u = ((const uint2*)(ffb + rowoff))[tid];
    float4 s;
    s.x = (float)pk.h4[0] + (float)pf.h4[0];
    s.y = (float)pk.h4[1] + (float)pf.h4[1];
    s.z = (float)pk.h4[2] + (float)pf.h4[2];
    s.w = (float)pk.h4[3] + (float)pf.h4[3];
    float sum = s.x + s.y + s.z + s.w;
    float sq = s.x * s.x + s.y * s.y + s.z * s.z + s.w * s.w;
    __shared__ float rs_[4], rq_[4];
    for (int off = 32; off; off >>= 1) {
        sum += __shfl_down(sum, off, 64);
        sq += __shfl_down(sq, off, 64);
    }
    if (lane == 0) { rs_[wave] = sum; rq_[wave] = sq; }
    __syncthreads();
    sum = rs_[0] + rs_[1] + rs_[2] + rs_[3];
    sq = rq_[0] + rq_[1] + rq_[2] + rq_[3];
    float mu = sum * (1.f / ND);
    float var = sq * (1.f / ND) - mu * mu;
    float rstd = rsqrtf(var + LNEPS);
    float4 g = ((const float4*)g2)[tid];
    float4 bb = ((const float4*)b2)[tid];
    float4 o;
    o.x = (s.x - mu) * rstd * g.x + bb.x;
    o.y = (s.y - mu) * rstd * g.y + bb.y;
    o.z = (s.z - mu) * rstd * g.z + bb.z;
    o.w = (s.w - mu) * rstd * g.w + bb.w;
    ((float4*)(out + rowoff))[tid] = o;
}

extern "C" void kernel_launch(void* const* d_in, const int* in_sizes, int n_in,
                              void* d_out, int out_size, void* d_ws, size_t ws_size,
                              hipStream_t stream) {
    const float* x  = (const float*)d_in[0];
    const float* Wq = (const float*)d_in[1];
    const float* Wk = (const float*)d_in[2];
    const float* Wv = (const float*)d_in[3];
    const float* W1 = (const float*)d_in[4];
    const float* W2 = (const float*)d_in[5];
    const float* g1 = (const float*)d_in[6];
    const float* b1 = (const float*)d_in[7];
    const float* g2 = (const float*)d_in[8];
    const float* b2 = (const float*)d_in[9];
    float* out = (float*)d_out;

    char* w = (char*)d_ws;
    float* xsum = (float*)w;   w += (size_t)NB * ND * 4;            // 32 KB
    float* vsum = (float*)w;   w += (size_t)NB * NH * NDH * 4;      // 32 KB
    float* wqk  = (float*)w;   w += (size_t)NB * NH * ND * 4;       // 512 KB
    float* rsum = (float*)w;   w += (size_t)NB * NH * NT * 4;       // 512 KB
    __bf16* x1b = (__bf16*)w;  w += (size_t)NM * ND * 2;            // 16 MB
    __bf16* h1b = (__bf16*)w;  w += (size_t)NM * ND * 2;            // 16 MB
    __bf16* ffb = (__bf16*)w;  w += (size_t)NM * ND * 2;            // 16 MB
    __bf16* w1t = (__bf16*)w;  w += (size_t)ND * ND * 2;            // 2 MB
    __bf16* w2t = (__bf16*)w;  w += (size_t)ND * ND * 2;            // 2 MB

    // zero xsum accumulator (ws is poisoned 0xAA before every launch)
    hipMemsetAsync(xsum, 0, (size_t)NB * ND * 4, stream);

    // weight transpose+convert (f32 KxN -> bf16 NxK), W1 and W2 in one dispatch
    transpose_to_bf16<<<dim3(32, 32, 2), dim3(32, 8), 0, stream>>>(W1, W2, w1t, w2t);

    // attention (algebraically reduced)
    xsum_kernel<<<dim3(NB, 64), 256, 0, stream>>>(x, xsum);
    head_prep<<<dim3(NH, NB), 256, 0, stream>>>(xsum, Wq, Wk, Wv, vsum, wqk);
    rowsum_kernel<<<dim3(64, NB), 256, 0, stream>>>(x, wqk, rsum);
    softmax_kernel<<<NB * NH, 256, 0, stream>>>(rsum);
    ln1_kernel<<<dim3(NT, NB), 256, 0, stream>>>(x, rsum, vsum, g1, b1, x1b);

    // FFN
    gemm_bf16<1><<<512, 256, 0, stream>>>(x1b, w1t, h1b);
    gemm_bf16<0><<<512, 256, 0, stream>>>(h1b, w2t, ffb);
    ln2_kernel<<<dim3(NT, NB), 256, 0, stream>>>(x1b, ffb, out, g2, b2);
}